// Round 2
// baseline (40249.744 us; speedup 1.0000x reference)
//
#include <hip/hip_runtime.h>

// GRU encoder-decoder, "transposed" persistent design.
// 256 blocks x 512 threads (8 waves). Block owns 32 batches (b = lane%32).
// Wave w, half s: group g = 2w+s owns hidden units j in {4g..4g+3}, i.e.
// gate rows {4g+c, 64+4g+c, 128+4g+c}. Weight reads are uniform within a
// half-wave (HW broadcast, natural row-major layout, immediate offsets).
// h0/h1 in LDS [k][b] (k-major, 32-wide): reads broadcast, writes 2-way-free.
// 2 barriers per step. Weight traffic: 147 KB/block/step (L1/L2 resident).

#define NB 32   // batches per block

__device__ __forceinline__ float sgm(float v) { return 1.f / (1.f + __expf(-v)); }
__device__ __forceinline__ float th(float v)  { float e = __expf(2.f * v); return 1.f - 2.f / (e + 1.f); }

struct P {
  const float *x;
  const float *eWi0, *eWh0, *ebi0, *ebh0, *eWi1, *eWh1, *ebi1, *ebh1;
  const float *dWi0, *dWh0, *dbi0, *dbh0, *dWi1, *dWh1, *dbi1, *dbh1;
  const float *oW, *ob;
  float *out;
};

// 12-row matvec over h[64] (regs). W natural [192][64] row-major; roff[i] is the
// float offset of row i's start. 16 dwordx4 loads per row at immediate offsets.
__device__ __forceinline__ void mv12(const float* __restrict__ W, const int* roff,
                                     const float* h, float acc[12]) {
#pragma unroll
  for (int i = 0; i < 12; ++i) {
    const float4* wp = (const float4*)(W + roff[i]);
    float a0 = 0.f, a1 = 0.f, a2 = 0.f, a3 = 0.f;
#pragma unroll
    for (int kc = 0; kc < 16; ++kc) {
      float4 wv = wp[kc];
      a0 += wv.x * h[kc * 4 + 0];
      a1 += wv.y * h[kc * 4 + 1];
      a2 += wv.z * h[kc * 4 + 2];
      a3 += wv.w * h[kc * 4 + 3];
    }
    acc[i] += (a0 + a1) + (a2 + a3);
  }
}

// load the 64 h values for this lane's batch from LDS (broadcast reads)
__device__ __forceinline__ void ldh(const float* hs, int bl, float* h) {
#pragma unroll
  for (int k = 0; k < 64; ++k) h[k] = hs[k * NB + bl];
}

__global__ __launch_bounds__(512, 2) void gru_main(P p) {
  __shared__ float h0s[64 * NB];
  __shared__ float h1s[64 * NB];
  __shared__ float ps[8 * NB];

  const int tid = threadIdx.x;
  const int w = tid >> 6;            // wave 0..7
  const int s = (tid >> 5) & 1;      // half 0/1
  const int bl = tid & 31;           // batch lane 0..31
  const int g = w * 2 + s;           // group 0..15, owns j in {4g..4g+3}
  const int b = blockIdx.x * NB + bl;

  int roff[12];                      // row float-offsets; idx = q*4+c (q: gate r/z/n)
#pragma unroll
  for (int q = 0; q < 3; ++q)
#pragma unroll
    for (int c = 0; c < 4; ++c) roff[q * 4 + c] = (q * 64 + g * 4 + c) * 64;

  // zero h state
#pragma unroll
  for (int i = 0; i < 4; ++i) {
    h0s[tid + i * 512] = 0.f;
    h1s[tid + i * 512] = 0.f;
  }
  __syncthreads();

  const float ob = p.ob[0];

  // ================= encoder =================
  {
    // per-lane constants: input weights (192x2) and folded biases
    float2 wx[12];
    float bf0[8], biN0[4], bhN0[4];   // cell0: folded r/z bias, split n bias
    float bf1[8], biN1[4], bhN1[4];   // cell1
#pragma unroll
    for (int i = 0; i < 12; ++i) {
      int r = roff[i] >> 6;  // row index
      wx[i] = *(const float2*)(p.eWi0 + r * 2);
      if (i < 8) { bf0[i] = p.ebi0[r] + p.ebh0[r]; bf1[i] = p.ebi1[r] + p.ebh1[r]; }
      else       { biN0[i - 8] = p.ebi0[r]; bhN0[i - 8] = p.ebh0[r];
                   biN1[i - 8] = p.ebi1[r]; bhN1[i - 8] = p.ebh1[r]; }
    }

    for (int t = 0; t < 512; ++t) {
      // ---- cell0 ----
      float h[64];
      ldh(h0s, bl, h);
      float acc[12];
#pragma unroll
      for (int i = 0; i < 12; ++i) acc[i] = 0.f;
      mv12(p.eWh0, roff, h, acc);
      float2 xt = *(const float2*)(p.x + ((size_t)b * 512 + t) * 2);
#pragma unroll
      for (int c = 0; c < 4; ++c) {
        float gr = wx[c].x * xt.x + wx[c].y * xt.y;
        float gz = wx[4 + c].x * xt.x + wx[4 + c].y * xt.y;
        float gn = wx[8 + c].x * xt.x + wx[8 + c].y * xt.y;
        float r = sgm(acc[c] + gr + bf0[c]);
        float z = sgm(acc[4 + c] + gz + bf0[4 + c]);
        float n = th(gn + biN0[c] + r * (acc[8 + c] + bhN0[c]));
        float hn = (1.f - z) * n + z * h[g * 4 + c];
        h0s[(g * 4 + c) * NB + bl] = hn;
      }
      __syncthreads();

      // ---- cell1 ----
      ldh(h0s, bl, h);                 // h0 new
      float ai[12];
#pragma unroll
      for (int i = 0; i < 12; ++i) ai[i] = 0.f;
      mv12(p.eWi1, roff, h, ai);       // gi = Wih1 @ h0new
      ldh(h1s, bl, h);                 // h1 old (also used for blend)
      float ah[12];
#pragma unroll
      for (int i = 0; i < 12; ++i) ah[i] = 0.f;
      mv12(p.eWh1, roff, h, ah);       // gh = Whh1 @ h1
#pragma unroll
      for (int c = 0; c < 4; ++c) {
        float r = sgm(ai[c] + ah[c] + bf1[c]);
        float z = sgm(ai[4 + c] + ah[4 + c] + bf1[4 + c]);
        float n = th(ai[8 + c] + biN1[c] + r * (ah[8 + c] + bhN1[c]));
        float hn = (1.f - z) * n + z * h[g * 4 + c];
        h1s[(g * 4 + c) * NB + bl] = hn;
      }
      __syncthreads();
    }
  }

  // ================= decoder =================
  {
    float wd[12];                      // dec Wih0 is (192,1)
    float bf0[8], biN0[4], bhN0[4];
    float bf1[8], biN1[4], bhN1[4];
    float oW4[4];
#pragma unroll
    for (int i = 0; i < 12; ++i) {
      int r = roff[i] >> 6;
      wd[i] = p.dWi0[r];
      if (i < 8) { bf0[i] = p.dbi0[r] + p.dbh0[r]; bf1[i] = p.dbi1[r] + p.dbh1[r]; }
      else       { biN0[i - 8] = p.dbi0[r]; bhN0[i - 8] = p.dbh0[r];
                   biN1[i - 8] = p.dbi1[r]; bhN1[i - 8] = p.dbh1[r]; }
    }
#pragma unroll
    for (int c = 0; c < 4; ++c) oW4[c] = p.oW[g * 4 + c];

    float prev = 0.f;
    for (int t = 0; t < 180; ++t) {
      // ---- cell0 (input = prev scalar) ----
      float h[64];
      ldh(h0s, bl, h);
      float acc[12];
#pragma unroll
      for (int i = 0; i < 12; ++i) acc[i] = 0.f;
      mv12(p.dWh0, roff, h, acc);
#pragma unroll
      for (int c = 0; c < 4; ++c) {
        float r = sgm(acc[c] + wd[c] * prev + bf0[c]);
        float z = sgm(acc[4 + c] + wd[4 + c] * prev + bf0[4 + c]);
        float n = th(wd[8 + c] * prev + biN0[c] + r * (acc[8 + c] + bhN0[c]));
        float hn = (1.f - z) * n + z * h[g * 4 + c];
        h0s[(g * 4 + c) * NB + bl] = hn;
      }
      __syncthreads();

      // ---- cell1 ----
      ldh(h0s, bl, h);
      float ai[12];
#pragma unroll
      for (int i = 0; i < 12; ++i) ai[i] = 0.f;
      mv12(p.dWi1, roff, h, ai);
      ldh(h1s, bl, h);
      float ah[12];
#pragma unroll
      for (int i = 0; i < 12; ++i) ah[i] = 0.f;
      mv12(p.dWh1, roff, h, ah);
      float hn1[4];
#pragma unroll
      for (int c = 0; c < 4; ++c) {
        float r = sgm(ai[c] + ah[c] + bf1[c]);
        float z = sgm(ai[4 + c] + ah[4 + c] + bf1[4 + c]);
        float n = th(ai[8 + c] + biN1[c] + r * (ah[8 + c] + bhN1[c]));
        hn1[c] = (1.f - z) * n + z * h[g * 4 + c];
        h1s[(g * 4 + c) * NB + bl] = hn1[c];
      }

      // ---- output dot: out[b] = sum_j oW[j]*h1new[j][b] + ob ----
      float pv = oW4[0] * hn1[0] + oW4[1] * hn1[1] + oW4[2] * hn1[2] + oW4[3] * hn1[3];
      pv += __shfl_xor(pv, 32, 64);          // combine the wave's two j-groups
      if (s == 0) ps[w * NB + bl] = pv;      // per-wave partial
      __syncthreads();                        // barrier: ps ready AND h writes drained
      float sum = ob;
#pragma unroll
      for (int q = 0; q < 8; ++q) sum += ps[q * NB + bl];
      prev = sum;                             // every lane gets its batch's prev
      if (g == 0) p.out[(size_t)b * 180 + t] = sum;
      // next step's h0s writes happen after the next mid-step barrier; all reads
      // of ps/h done by then -> no extra barrier needed here.
    }
  }
}

extern "C" void kernel_launch(void* const* d_in, const int* in_sizes, int n_in,
                              void* d_out, int out_size, void* d_ws, size_t ws_size,
                              hipStream_t stream) {
  P p;
  p.x    = (const float*)d_in[0];
  p.eWi0 = (const float*)d_in[1];
  p.eWh0 = (const float*)d_in[2];
  p.ebi0 = (const float*)d_in[3];
  p.ebh0 = (const float*)d_in[4];
  p.eWi1 = (const float*)d_in[5];
  p.eWh1 = (const float*)d_in[6];
  p.ebi1 = (const float*)d_in[7];
  p.ebh1 = (const float*)d_in[8];
  p.dWi0 = (const float*)d_in[9];
  p.dWh0 = (const float*)d_in[10];
  p.dbi0 = (const float*)d_in[11];
  p.dbh0 = (const float*)d_in[12];
  p.dWi1 = (const float*)d_in[13];
  p.dWh1 = (const float*)d_in[14];
  p.dbi1 = (const float*)d_in[15];
  p.dbh1 = (const float*)d_in[16];
  p.oW   = (const float*)d_in[17];
  p.ob   = (const float*)d_in[18];
  p.out  = (float*)d_out;

  gru_main<<<dim3(256), dim3(512), 0, stream>>>(p);
}